// Round 1
// baseline (281.965 us; speedup 1.0000x reference)
//
#include <hip/hip_runtime.h>
#include <math.h>

#define B 8192
#define D 128
#define BM 128
#define BN 128
#define KC 16
#define NCHUNK 8
#define COLS_PER_CHUNK (B / NCHUNK) /* 1024 */
#define NCT (COLS_PER_CHUNK / BN)   /* 8 */
#define MARGIN 1.0f

// ws layout (floats):
//   sqn : [0, B)
//   ppos: [B, B + NCHUNK*B)
//   pneg: [B + NCHUNK*B, B + 2*NCHUNK*B)

__global__ void mmcl_sqn_kernel(const float* __restrict__ X,
                                float* __restrict__ sqn,
                                float* __restrict__ out) {
    const int wave = threadIdx.x >> 6;
    const int lane = threadIdx.x & 63;
    const int row  = blockIdx.x * 4 + wave;
    const float2 v = *(const float2*)(X + (size_t)row * D + lane * 2);
    float s = v.x * v.x + v.y * v.y;
    #pragma unroll
    for (int off = 32; off; off >>= 1) s += __shfl_down(s, off);
    if (lane == 0) sqn[row] = s;
    if (blockIdx.x == 0 && threadIdx.x == 0) *out = 0.0f;  // zero the loss accumulator
}

__global__ __launch_bounds__(256, 2) void mmcl_tile_kernel(
    const float* __restrict__ X, const int* __restrict__ lab,
    const float* __restrict__ sqn,
    float* __restrict__ ppos, float* __restrict__ pneg)
{
    __shared__ float lds_a[KC][BM];  // K-major: lds_a[k][row]
    __shared__ float lds_b[KC][BN];
    __shared__ int   lds_lab[BN];

    const int tid  = threadIdx.x;
    const int tx   = tid & 15;
    const int ty   = tid >> 4;
    const int R    = blockIdx.x * BM;
    const int chnk = blockIdx.y;
    const int r0   = ty * 8;
    const int c0   = tx * 8;

    int labR[8];
    #pragma unroll
    for (int i = 0; i < 8; ++i) labR[i] = lab[R + r0 + i];

    float minpos[8], maxneg[8];
    #pragma unroll
    for (int i = 0; i < 8; ++i) { minpos[i] = INFINITY; maxneg[i] = -INFINITY; }

    const int sr = tid >> 1;        // staging row in tile (0..127)
    const int sh = (tid & 1) * 8;   // staging k offset (0 or 8)

    for (int ct = 0; ct < NCT; ++ct) {
        const int C = chnk * COLS_PER_CHUNK + ct * BN;
        __syncthreads();                       // protect lds_lab + last tile's lds readers
        if (tid < BN) lds_lab[tid] = lab[C + tid];

        float acc[8][8];
        #pragma unroll
        for (int i = 0; i < 8; ++i)
            #pragma unroll
            for (int j = 0; j < 8; ++j) acc[i][j] = 0.f;

        for (int kc = 0; kc < D / KC; ++kc) {
            __syncthreads();
            {   // stage A chunk (16 k x 128 rows), K-major
                const float4* g = (const float4*)(X + (size_t)(R + sr) * D + kc * KC + sh);
                const float4 v0 = g[0], v1 = g[1];
                lds_a[sh + 0][sr] = v0.x; lds_a[sh + 1][sr] = v0.y;
                lds_a[sh + 2][sr] = v0.z; lds_a[sh + 3][sr] = v0.w;
                lds_a[sh + 4][sr] = v1.x; lds_a[sh + 5][sr] = v1.y;
                lds_a[sh + 6][sr] = v1.z; lds_a[sh + 7][sr] = v1.w;
            }
            {   // stage B chunk
                const float4* g = (const float4*)(X + (size_t)(C + sr) * D + kc * KC + sh);
                const float4 v0 = g[0], v1 = g[1];
                lds_b[sh + 0][sr] = v0.x; lds_b[sh + 1][sr] = v0.y;
                lds_b[sh + 2][sr] = v0.z; lds_b[sh + 3][sr] = v0.w;
                lds_b[sh + 4][sr] = v1.x; lds_b[sh + 5][sr] = v1.y;
                lds_b[sh + 6][sr] = v1.z; lds_b[sh + 7][sr] = v1.w;
            }
            __syncthreads();
            #pragma unroll
            for (int kk = 0; kk < KC; ++kk) {
                const float4 a0 = *(const float4*)&lds_a[kk][r0];
                const float4 a1 = *(const float4*)&lds_a[kk][r0 + 4];
                const float4 b0 = *(const float4*)&lds_b[kk][c0];
                const float4 b1 = *(const float4*)&lds_b[kk][c0 + 4];
                const float a[8] = {a0.x,a0.y,a0.z,a0.w,a1.x,a1.y,a1.z,a1.w};
                const float b[8] = {b0.x,b0.y,b0.z,b0.w,b1.x,b1.y,b1.z,b1.w};
                #pragma unroll
                for (int i = 0; i < 8; ++i)
                    #pragma unroll
                    for (int j = 0; j < 8; ++j)
                        acc[i][j] = fmaf(a[i], b[j], acc[i][j]);
            }
        }

        // epilogue for this 128x128 tile: fold into running min/max of (sq_j - 2*dot)
        const float4 sc0 = *(const float4*)(sqn + C + c0);
        const float4 sc1 = *(const float4*)(sqn + C + c0 + 4);
        const float sq_c[8] = {sc0.x,sc0.y,sc0.z,sc0.w,sc1.x,sc1.y,sc1.z,sc1.w};
        #pragma unroll
        for (int j = 0; j < 8; ++j) {
            const int lc = lds_lab[c0 + j];
            const int gj = C + c0 + j;
            #pragma unroll
            for (int i = 0; i < 8; ++i) {
                const float v    = fmaf(-2.f, acc[i][j], sq_c[j]);
                const bool same  = (labR[i] == lc);
                const bool diag  = ((R + r0 + i) == gj);
                if (same && !diag) minpos[i] = fminf(minpos[i], v);
                if (!same)         maxneg[i] = fmaxf(maxneg[i], v);
            }
        }
    }

    // reduce across the 16 tx lanes sharing each row (xor butterfly within wave)
    #pragma unroll
    for (int i = 0; i < 8; ++i) {
        float mp = minpos[i], mn = maxneg[i];
        #pragma unroll
        for (int off = 1; off < 16; off <<= 1) {
            mp = fminf(mp, __shfl_xor(mp, off));
            mn = fmaxf(mn, __shfl_xor(mn, off));
        }
        if (tx == 0) {
            ppos[(size_t)chnk * B + R + r0 + i] = mp;
            pneg[(size_t)chnk * B + R + r0 + i] = mn;
        }
    }
}

__global__ void mmcl_final_kernel(const float* __restrict__ sqn,
                                  const float* __restrict__ ppos,
                                  const float* __restrict__ pneg,
                                  float* __restrict__ out)
{
    const int row = blockIdx.x * 256 + threadIdx.x;
    float mp = INFINITY, mn = -INFINITY;
    #pragma unroll
    for (int c = 0; c < NCHUNK; ++c) {
        mp = fminf(mp, ppos[(size_t)c * B + row]);
        mn = fmaxf(mn, pneg[(size_t)c * B + row]);
    }
    const float sq  = sqn[row];
    const float pos = isinf(mp) ? INFINITY : sqrtf(fmaxf(sq + mp, 0.f));
    const float neg = (mn == -INFINITY) ? -INFINITY : sqrtf(fmaxf(sq + mn, 0.f));
    const float term = fmaxf(pos - neg + MARGIN, 0.f);

    float s = term;
    #pragma unroll
    for (int off = 32; off; off >>= 1) s += __shfl_down(s, off);
    __shared__ float wsum[4];
    const int wave = threadIdx.x >> 6, lane = threadIdx.x & 63;
    if (lane == 0) wsum[wave] = s;
    __syncthreads();
    if (threadIdx.x == 0) {
        atomicAdd(out, (wsum[0] + wsum[1] + wsum[2] + wsum[3]) * (1.0f / B));
    }
}

extern "C" void kernel_launch(void* const* d_in, const int* in_sizes, int n_in,
                              void* d_out, int out_size, void* d_ws, size_t ws_size,
                              hipStream_t stream) {
    (void)in_sizes; (void)n_in; (void)out_size; (void)ws_size;
    const float* X   = (const float*)d_in[0];
    const int*   lab = (const int*)d_in[1];
    float* out = (float*)d_out;

    float* sqn  = (float*)d_ws;
    float* ppos = sqn + B;
    float* pneg = ppos + (size_t)NCHUNK * B;

    mmcl_sqn_kernel<<<B / 4, 256, 0, stream>>>(X, sqn, out);
    mmcl_tile_kernel<<<dim3(B / BM, NCHUNK), 256, 0, stream>>>(X, lab, sqn, ppos, pneg);
    mmcl_final_kernel<<<B / 256, 256, 0, stream>>>(sqn, ppos, pneg, out);
}

// Round 2
// 111.846 us; speedup vs baseline: 2.5210x; 2.5210x over previous
//
#include <hip/hip_runtime.h>
#include <hip/hip_bf16.h>
#include <math.h>

#define B 8192
#define D 128
#define NCHUNK 16
#define CPC (B / NCHUNK)   /* 512 cols per chunk */
#define CT 64              /* cols per LDS tile */
#define NCT (CPC / CT)     /* 8 tiles per chunk */
#define BROWS 256          /* rows per block (4 waves x 64) */
#define MARGIN 1.0f

typedef short short8 __attribute__((ext_vector_type(8)));
typedef float f32x4 __attribute__((ext_vector_type(4)));

// ws layout (floats):
//   sqn [B] | ppos [NCHUNK*B] | pneg [NCHUNK*B] | Xh (ushort, B*256: hi|lo bf16, swizzled)

__device__ inline ushort f2bf(float f) {
    __hip_bfloat16 h = __float2bfloat16(f);
    ushort u; __builtin_memcpy(&u, &h, 2); return u;
}
__device__ inline float bf2f(ushort u) {
    unsigned int i = ((unsigned)u) << 16; float f; __builtin_memcpy(&f, &i, 4); return f;
}

__device__ inline void gload_lds16(const void* gsrc, void* ldst) {
    __builtin_amdgcn_global_load_lds(
        (const __attribute__((address_space(1))) unsigned int*)gsrc,
        (__attribute__((address_space(3))) unsigned int*)ldst,
        16, 0, 0);
}

__global__ void mmcl_sqn_kernel(const float* __restrict__ X,
                                float* __restrict__ sqn,
                                float* __restrict__ out) {
    const int wave = threadIdx.x >> 6;
    const int lane = threadIdx.x & 63;
    const int row  = blockIdx.x * 4 + wave;
    const float2 v = *(const float2*)(X + (size_t)row * D + lane * 2);
    float s = v.x * v.x + v.y * v.y;
    #pragma unroll
    for (int off = 32; off; off >>= 1) s += __shfl_down(s, off);
    if (lane == 0) sqn[row] = s;
    if (blockIdx.x == 0 && threadIdx.x == 0) *out = 0.0f;
}

// Split each fp32 row into bf16 hi|lo, stored pre-swizzled in 16B granules:
// logical granule g (0..31: 0-15 hi, 16-31 lo) of row r lands at granule g ^ (r&7).
__global__ void mmcl_prep_kernel(const float* __restrict__ X,
                                 ushort* __restrict__ Xh) {
    const int t  = blockIdx.x * 256 + threadIdx.x;
    const int r  = t >> 4;
    const int kg = t & 15;
    const float4 v0 = *(const float4*)(X + (size_t)r * D + kg * 8);
    const float4 v1 = *(const float4*)(X + (size_t)r * D + kg * 8 + 4);
    const float xs[8] = {v0.x, v0.y, v0.z, v0.w, v1.x, v1.y, v1.z, v1.w};
    short8 hv, lv;
    #pragma unroll
    for (int i = 0; i < 8; ++i) {
        const float x = xs[i];
        const ushort h = f2bf(x);
        hv[i] = (short)h;
        lv[i] = (short)f2bf(x - bf2f(h));
    }
    const int s = r & 7;
    ushort* rp = Xh + (size_t)r * 256;
    *(short8*)(rp + ((kg ^ s) << 3))        = hv;
    *(short8*)(rp + (((16 + kg) ^ s) << 3)) = lv;
}

__global__ __launch_bounds__(256, 2) void mmcl_mfma_kernel(
    const ushort* __restrict__ Xh, const float* __restrict__ sqn,
    const int* __restrict__ lab,
    float* __restrict__ ppos, float* __restrict__ pneg)
{
    __shared__ ushort lds[2][CT * 256];   // 2 x 32KB, hi|lo per col row, swizzled
    const int tid  = threadIdx.x;
    const int wid  = tid >> 6;
    const int lane = tid & 63;
    const int lhi  = lane >> 4;
    const int llo  = lane & 15;
    const int R    = blockIdx.x * BROWS + wid * 64;
    const int C0   = blockIdx.y * CPC;

    // A fragments: rows R + m*16 + llo, all K=128 (hi+lo) resident in registers.
    short8 a_hi[4][4], a_lo[4][4];
    #pragma unroll
    for (int m = 0; m < 4; ++m) {
        const int row = R + m * 16 + llo;
        const int s = row & 7;
        const ushort* rp = Xh + (size_t)row * 256;
        #pragma unroll
        for (int kf = 0; kf < 4; ++kf) {
            const int g = kf * 4 + lhi;
            a_hi[m][kf] = *(const short8*)(rp + ((g ^ s) << 3));
            a_lo[m][kf] = *(const short8*)(rp + (((16 + g) ^ s) << 3));
        }
    }

    int labR[4][4];
    #pragma unroll
    for (int m = 0; m < 4; ++m)
        #pragma unroll
        for (int r = 0; r < 4; ++r)
            labR[m][r] = lab[R + m * 16 + lhi * 4 + r];

    float minpos[4][4], maxneg[4][4];
    #pragma unroll
    for (int m = 0; m < 4; ++m)
        #pragma unroll
        for (int r = 0; r < 4; ++r) { minpos[m][r] = INFINITY; maxneg[m][r] = -INFINITY; }

    // stage tile t into buf: 32KB contiguous; wave wid copies its 8KB slice, 8x1KB issues
    auto stage = [&](int buf, int t) {
        const char* g = (const char*)(Xh + (size_t)(C0 + t * CT) * 256) + wid * 8192 + lane * 16;
        char* l = (char*)&lds[buf][0] + wid * 8192;
        #pragma unroll
        for (int i = 0; i < 8; ++i)
            gload_lds16(g + i * 1024, l + i * 1024);
    };

    stage(0, 0);

    for (int t = 0; t < NCT; ++t) {
        const int cur = t & 1;
        __syncthreads();                     // drains stage(cur); all waves done reading cur^1
        if (t + 1 < NCT) stage(cur ^ 1, t + 1);

        const int colbase = C0 + t * CT;
        #pragma unroll
        for (int n = 0; n < 4; ++n) {
            const int cl = n * 16 + llo;     // local col row; (global col)&7 == cl&7
            const int s = cl & 7;
            const ushort* bp = &lds[cur][cl * 256];
            f32x4 acc[4];
            #pragma unroll
            for (int m = 0; m < 4; ++m) acc[m] = (f32x4){0.f, 0.f, 0.f, 0.f};

            #pragma unroll
            for (int kf = 0; kf < 4; ++kf) {
                const int g = kf * 4 + lhi;
                const short8 b_hi = *(const short8*)(bp + ((g ^ s) << 3));
                const short8 b_lo = *(const short8*)(bp + (((16 + g) ^ s) << 3));
                #pragma unroll
                for (int m = 0; m < 4; ++m) {
                    acc[m] = __builtin_amdgcn_mfma_f32_16x16x32_bf16(a_hi[m][kf], b_hi, acc[m], 0, 0, 0);
                    acc[m] = __builtin_amdgcn_mfma_f32_16x16x32_bf16(a_hi[m][kf], b_lo, acc[m], 0, 0, 0);
                    acc[m] = __builtin_amdgcn_mfma_f32_16x16x32_bf16(a_lo[m][kf], b_hi, acc[m], 0, 0, 0);
                }
            }

            // epilogue: fold v = sq_j - 2*dot into per-row running min/max
            const int col  = colbase + cl;
            const float sqc = sqn[col];
            const int   lc  = lab[col];
            #pragma unroll
            for (int m = 0; m < 4; ++m) {
                const int rowb = R + m * 16 + lhi * 4;
                #pragma unroll
                for (int r = 0; r < 4; ++r) {
                    const float v = fmaf(-2.0f, acc[m][r], sqc);
                    const bool same = (labR[m][r] == lc);
                    const bool diag = (rowb + r == col);
                    if (same && !diag) minpos[m][r] = fminf(minpos[m][r], v);
                    if (!same)         maxneg[m][r] = fmaxf(maxneg[m][r], v);
                }
            }
        }
    }

    // reduce across the 16 llo lanes of each lhi group (cols), write per-chunk partials
    #pragma unroll
    for (int m = 0; m < 4; ++m)
        #pragma unroll
        for (int r = 0; r < 4; ++r) {
            float mp = minpos[m][r], mn = maxneg[m][r];
            #pragma unroll
            for (int off = 1; off < 16; off <<= 1) {
                mp = fminf(mp, __shfl_xor(mp, off));
                mn = fmaxf(mn, __shfl_xor(mn, off));
            }
            if (llo == 0) {
                const int row = R + m * 16 + lhi * 4 + r;
                ppos[(size_t)blockIdx.y * B + row] = mp;
                pneg[(size_t)blockIdx.y * B + row] = mn;
            }
        }
}

__global__ void mmcl_final_kernel(const float* __restrict__ sqn,
                                  const float* __restrict__ ppos,
                                  const float* __restrict__ pneg,
                                  float* __restrict__ out)
{
    const int row = blockIdx.x * 256 + threadIdx.x;
    float mp = INFINITY, mn = -INFINITY;
    #pragma unroll
    for (int c = 0; c < NCHUNK; ++c) {
        mp = fminf(mp, ppos[(size_t)c * B + row]);
        mn = fmaxf(mn, pneg[(size_t)c * B + row]);
    }
    const float sq  = sqn[row];
    const float pos = isinf(mp) ? INFINITY : sqrtf(fmaxf(sq + mp, 0.f));
    const float neg = (mn == -INFINITY) ? -INFINITY : sqrtf(fmaxf(sq + mn, 0.f));
    const float term = fmaxf(pos - neg + MARGIN, 0.f);

    float s = term;
    #pragma unroll
    for (int off = 32; off; off >>= 1) s += __shfl_down(s, off);
    __shared__ float wsum[4];
    const int wave = threadIdx.x >> 6, lane = threadIdx.x & 63;
    if (lane == 0) wsum[wave] = s;
    __syncthreads();
    if (threadIdx.x == 0)
        atomicAdd(out, (wsum[0] + wsum[1] + wsum[2] + wsum[3]) * (1.0f / B));
}

extern "C" void kernel_launch(void* const* d_in, const int* in_sizes, int n_in,
                              void* d_out, int out_size, void* d_ws, size_t ws_size,
                              hipStream_t stream) {
    (void)in_sizes; (void)n_in; (void)out_size; (void)ws_size;
    const float* X   = (const float*)d_in[0];
    const int*   lab = (const int*)d_in[1];
    float* out = (float*)d_out;

    float*  sqn  = (float*)d_ws;
    float*  ppos = sqn + B;
    float*  pneg = ppos + (size_t)NCHUNK * B;
    ushort* Xh   = (ushort*)(pneg + (size_t)NCHUNK * B);   // 16B-aligned (33*B floats)

    mmcl_sqn_kernel<<<B / 4, 256, 0, stream>>>(X, sqn, out);
    mmcl_prep_kernel<<<(B * 16) / 256, 256, 0, stream>>>(X, Xh);
    mmcl_mfma_kernel<<<dim3(B / BROWS, NCHUNK), 256, 0, stream>>>(Xh, sqn, lab, ppos, pneg);
    mmcl_final_kernel<<<B / 256, 256, 0, stream>>>(sqn, ppos, pneg, out);
}